// Round 3
// baseline (666.567 us; speedup 1.0000x reference)
//
#include <hip/hip_runtime.h>

#define Bdim 2
#define Hdim 8
#define Sdim 2048
#define Ddim 64
#define PSTR 2056   // P row stride in shorts: +8 pad breaks 16-way bank aliasing
#define NW 8        // waves per block (512 threads)

typedef short bf16x8 __attribute__((ext_vector_type(8)));
typedef short bf16x4 __attribute__((ext_vector_type(4)));
typedef float f32x4 __attribute__((ext_vector_type(4)));

// float -> bf16 bits via hardware cvt (RNE; v_cvt_pk_bf16_f32)
static __device__ __forceinline__ short f2bf(float x) {
  return __builtin_bit_cast(short, (__bf16)x);
}
static __device__ __forceinline__ float bf2f(short x) {
  unsigned u = ((unsigned)(unsigned short)x) << 16;
  return __builtin_bit_cast(float, u);
}
static __device__ __forceinline__ bf16x8 pack8(float4 a, float4 b, float s) {
  bf16x8 r;
  r[0] = f2bf(a.x * s); r[1] = f2bf(a.y * s);
  r[2] = f2bf(a.z * s); r[3] = f2bf(a.w * s);
  r[4] = f2bf(b.x * s); r[5] = f2bf(b.y * s);
  r[6] = f2bf(b.z * s); r[7] = f2bf(b.w * s);
  return r;
}
static __device__ __forceinline__ bf16x8 pack8n(float4 a, float4 b) {
  bf16x8 r;
  r[0] = f2bf(a.x); r[1] = f2bf(a.y); r[2] = f2bf(a.z); r[3] = f2bf(a.w);
  r[4] = f2bf(b.x); r[5] = f2bf(b.y); r[6] = f2bf(b.z); r[7] = f2bf(b.w);
  return r;
}

// Issue 8 vec loads of K rows [TROW, TROW+32) for this lane's B-frag.
#define LOADK(KD, TROW)                                                        \
  {                                                                            \
    const float* kr0 = kbase + (size_t)((TROW) + l15) * Ddim + quad * 8;       \
    KD[0] = *(const float4*)(kr0);                                             \
    KD[1] = *(const float4*)(kr0 + 4);                                         \
    KD[2] = *(const float4*)(kr0 + 32);                                        \
    KD[3] = *(const float4*)(kr0 + 36);                                        \
    const float* kr1 = kr0 + 16 * Ddim;                                        \
    KD[4] = *(const float4*)(kr1);                                             \
    KD[5] = *(const float4*)(kr1 + 4);                                         \
    KD[6] = *(const float4*)(kr1 + 32);                                        \
    KD[7] = *(const float4*)(kr1 + 36);                                        \
  }

// One 32-col tile. Issue order == consumption order (vmcnt is FIFO):
//  cov/mask (blend) and V (PV) issue at top, covered by QK MFMA phase;
//  K for the NEXT tile issues right after QK, covered by blend+exp+PV.
#define QK_BODY(KCUR, KNEXT, T0, TNEXT)                                        \
  {                                                                            \
    float cvf[2][4]; int mki[2][4];                                            \
    _Pragma("unroll") for (int n = 0; n < 2; ++n)                              \
      _Pragma("unroll") for (int r = 0; r < 4; ++r) {                          \
        const int col = (T0) + n * 16 + l15;                                   \
        cvf[n][r] = covb[(quad * 4 + r) * Sdim + col];                         \
        mki[n][r] = mb[(quad * 4 + r) * Sdim + col];                           \
      }                                                                        \
    bf16x8 bvv[4];                                                             \
    _Pragma("unroll") for (int nb = 0; nb < 4; ++nb) {                         \
      const float* vcol = vbase + (size_t)((T0) + quad * 8) * Ddim + nb * 16 + l15; \
      _Pragma("unroll") for (int j = 0; j < 8; ++j) bvv[nb][j] = f2bf(vcol[j * Ddim]); \
    }                                                                          \
    f32x4 acc[2];                                                              \
    _Pragma("unroll") for (int n = 0; n < 2; ++n) {                            \
      bf16x8 b0 = pack8n(KCUR[n * 4 + 0], KCUR[n * 4 + 1]);                    \
      bf16x8 b1 = pack8n(KCUR[n * 4 + 2], KCUR[n * 4 + 3]);                    \
      f32x4 a = {0.f, 0.f, 0.f, 0.f};                                          \
      a = __builtin_amdgcn_mfma_f32_16x16x32_bf16(aq0, b0, a, 0, 0, 0);        \
      a = __builtin_amdgcn_mfma_f32_16x16x32_bf16(aq1, b1, a, 0, 0, 0);        \
      acc[n] = a;                                                              \
    }                                                                          \
    LOADK(KNEXT, TNEXT);                                                       \
    _Pragma("unroll") for (int n = 0; n < 2; ++n) {                            \
      const int col = (T0) + n * 16 + l15;                                     \
      _Pragma("unroll") for (int r = 0; r < 4; ++r) {                          \
        const int row = quad * 4 + r;                                          \
        float logit = acc[n][r] + w_cov * cvf[n][r];                           \
        float p = mki[n][r] ? __expf(logit) : 0.0f;                            \
        lsum[r] += p;                                                          \
        Pl[row][col] = f2bf(p);                                                \
      }                                                                        \
    }                                                                          \
    bf16x8 pa = *(const bf16x8*)&Pl[l15][(T0) + quad * 8];                     \
    _Pragma("unroll") for (int nb = 0; nb < 4; ++nb)                           \
      oacc[nb] = __builtin_amdgcn_mfma_f32_16x16x32_bf16(pa, bvv[nb], oacc[nb], 0, 0, 0); \
  }

// One block = (b, h, 16-row q-tile). 8 waves; wave w owns t-cols [w*256, w*256+256).
// XCD-aware decode: dispatch round-robins bid%8 across the 8 XCDs, so we put
// the 8 heads sharing one (b,qt) cov/mask tile at the SAME bid%8 (same XCD,
// consecutive slots -> concurrent). cov/mask live set per XCD = 8 pairs
// x 256KB = 2MB < 4MB L2 -> fetched ~once per XCD instead of 8x. Same-(b,h)
// K/V sharers are adjacent pairs on the same XCD, temporally aligned.
__global__ __launch_bounds__(512, 4) void fused_attn(
    const float* __restrict__ qp, const float* __restrict__ kp,
    const float* __restrict__ vp, const float* __restrict__ covp,
    const float* __restrict__ lamp, const int* __restrict__ maskp,
    float* __restrict__ outO, float* __restrict__ outA)
{
  __shared__ __align__(16) short Pl[16][PSTR];  // 65792 B -> 2 blocks/CU
  __shared__ float Ls[NW][16];
  __shared__ float Lrow[16];

  const int tid  = threadIdx.x;
  const int wv   = tid >> 6;
  const int lane = tid & 63;
  const int quad = lane >> 4;
  const int l15  = lane & 15;

  const int bid  = blockIdx.x;
  const int xcd  = bid & 7;
  const int slot = bid >> 3;                 // 0..255 within this XCD
  const int h    = slot & 7;
  const int pair = xcd * 32 + (slot >> 3);   // 0..255 = (b, qt)
  const int b    = pair >> 7;
  const int qt   = pair & 127;

  const float lam   = lamp[h];
  const float w_qk  = 1.0f / (lam + 1.0f);
  const float w_cov = lam / (lam + 1.0f);
  const float qscale = w_qk * 0.125f;   // fold 1/TEMPERATURE and w_qk into Q

  const int q0 = qt * 16;
  const int bh = b * Hdim + h;

  const float* qbase = qp + ((size_t)bh * Sdim + q0) * Ddim;
  const float* kbase = kp + (size_t)bh * Sdim * Ddim;
  const float* vbase = vp + (size_t)bh * Sdim * Ddim;
  const float* covb  = covp + ((size_t)b * Sdim + q0) * Sdim;
  const int*   mb    = maskp + ((size_t)b * Sdim + q0) * Sdim;
  float* oA = outA + ((size_t)bh * Sdim + q0) * (size_t)Sdim;
  float* oO = outO + ((size_t)bh * Sdim + q0) * Ddim;

  // Q A-frag (16 rows x 64 k), pre-scaled: A[m=l15][k=quad*8+j]
  bf16x8 aq0, aq1;
  {
    const float* qr = qbase + l15 * Ddim + quad * 8;
    float4 x0 = *(const float4*)(qr);
    float4 x1 = *(const float4*)(qr + 4);
    aq0 = pack8(x0, x1, qscale);
    float4 y0 = *(const float4*)(qr + 32);
    float4 y1 = *(const float4*)(qr + 36);
    aq1 = pack8(y0, y1, qscale);
  }

  const int tbeg = wv * (Sdim / NW);
  const int tend = tbeg + (Sdim / NW);

  float lsum[4] = {0.f, 0.f, 0.f, 0.f};
  f32x4 oacc[4];
#pragma unroll
  for (int n = 0; n < 4; ++n) oacc[n] = (f32x4){0.f, 0.f, 0.f, 0.f};

  // Manual 2x unrolled A/B K-register double-buffer (no runtime-indexed
  // arrays; tend-tbeg = 256 -> 8 bodies -> 4 clean pairs).
  float4 kA[8], kB[8];
  LOADK(kA, tbeg);
#pragma unroll 1
  for (int t0 = tbeg; t0 < tend; t0 += 64) {
    QK_BODY(kA, kB, t0, t0 + 32);
    const int tnx = (t0 + 64 < tend) ? (t0 + 64) : tbeg;  // last prefetch: dummy
    QK_BODY(kB, kA, t0 + 32, tnx);
  }

  // ---- cross-wave row-sum reduction ----
#pragma unroll
  for (int r = 0; r < 4; ++r) {
    float s = lsum[r];
    s += __shfl_xor(s, 1, 16);
    s += __shfl_xor(s, 2, 16);
    s += __shfl_xor(s, 4, 16);
    s += __shfl_xor(s, 8, 16);
    if (l15 == 0) Ls[wv][quad * 4 + r] = s;
  }
  __syncthreads();
  if (tid < 16) {
    float s = 0.f;
#pragma unroll
    for (int w2 = 0; w2 < NW; ++w2) s += Ls[w2][tid];
    Lrow[tid] = 1.0f / s;
  }
  __syncthreads();

  // ---- normalize + write attn (each wave: its own 256-col slice, all 16 rows) ----
#pragma unroll 1
  for (int row = 0; row < 16; ++row) {
    const float rinv = Lrow[row];
    float* orow = oA + (size_t)row * Sdim;
    const int c0 = tbeg + lane * 4;
    bf16x4 pv = *(const bf16x4*)&Pl[row][c0];
    f32x4 o;
    o[0] = bf2f(pv[0]) * rinv;
    o[1] = bf2f(pv[1]) * rinv;
    o[2] = bf2f(pv[2]) * rinv;
    o[3] = bf2f(pv[3]) * rinv;
    __builtin_nontemporal_store(o, (f32x4*)&orow[c0]);
  }
  __syncthreads();   // all P reads done; safe to alias

  // ---- O reduction across waves (alias P region), scale by 1/l, store ----
  float* Ored = (float*)&Pl[0][0];   // [NW][64][16] f32 = 32 KB, fits in P alias
#pragma unroll
  for (int nb = 0; nb < 4; ++nb)
#pragma unroll
    for (int r = 0; r < 4; ++r)
      Ored[((wv * 64 + lane) * 16) + nb * 4 + r] = oacc[nb][r];
  __syncthreads();
  if (wv < 4) {
#pragma unroll
    for (int r = 0; r < 4; ++r) {
      float s = 0.f;
#pragma unroll
      for (int w2 = 0; w2 < NW; ++w2)
        s += Ored[((w2 * 64 + lane) * 16) + wv * 4 + r];
      const int row = quad * 4 + r;
      __builtin_nontemporal_store(s * Lrow[row], &oO[row * Ddim + wv * 16 + l15]);
    }
  }
}

extern "C" void kernel_launch(void* const* d_in, const int* in_sizes, int n_in,
                              void* d_out, int out_size, void* d_ws, size_t ws_size,
                              hipStream_t stream) {
  const float* q    = (const float*)d_in[0];
  const float* k    = (const float*)d_in[1];
  const float* v    = (const float*)d_in[2];
  const float* cov  = (const float*)d_in[3];
  const float* lam  = (const float*)d_in[4];
  const int*   mask = (const int*)d_in[5];
  float* outO = (float*)d_out;
  float* outA = outO + (size_t)Bdim * Hdim * Sdim * Ddim;
  (void)d_ws; (void)ws_size;

  dim3 grid(Bdim * Hdim * (Sdim / 16));   // 2048 blocks x 512 threads
  fused_attn<<<grid, 512, 0, stream>>>(q, k, v, cov, lam, mask, outO, outA);
}

// Round 4
// 502.772 us; speedup vs baseline: 1.3258x; 1.3258x over previous
//
#include <hip/hip_runtime.h>

#define Bdim 2
#define Hdim 8
#define Sdim 2048
#define Ddim 64
#define PSTR 2056   // P row stride in shorts: +8 pad breaks 16-way bank aliasing
#define NW 8        // waves per block (512 threads)

typedef short bf16x8 __attribute__((ext_vector_type(8)));
typedef short bf16x4 __attribute__((ext_vector_type(4)));
typedef float f32x4 __attribute__((ext_vector_type(4)));

// float -> bf16 bits via hardware cvt (RNE; v_cvt_pk_bf16_f32)
static __device__ __forceinline__ short f2bf(float x) {
  return __builtin_bit_cast(short, (__bf16)x);
}
static __device__ __forceinline__ float bf2f(short x) {
  unsigned u = ((unsigned)(unsigned short)x) << 16;
  return __builtin_bit_cast(float, u);
}
static __device__ __forceinline__ bf16x8 pack8(float4 a, float4 b, float s) {
  bf16x8 r;
  r[0] = f2bf(a.x * s); r[1] = f2bf(a.y * s);
  r[2] = f2bf(a.z * s); r[3] = f2bf(a.w * s);
  r[4] = f2bf(b.x * s); r[5] = f2bf(b.y * s);
  r[6] = f2bf(b.z * s); r[7] = f2bf(b.w * s);
  return r;
}

// ---------- pre-pass 1: K f32 -> bf16, same [b][h][t][d] layout ----------
__global__ __launch_bounds__(256) void cvt_k(const float* __restrict__ kp,
                                             short* __restrict__ kb) {
  size_t i = ((size_t)blockIdx.x * 256 + threadIdx.x) * 8;
  float4 x0 = *(const float4*)(kp + i);
  float4 x1 = *(const float4*)(kp + i + 4);
  bf16x8 r = pack8(x0, x1, 1.0f);
  *(bf16x8*)(kb + i) = r;
}

// ---------- pre-pass 2: V f32 [bh][t][d] -> bf16 [bh][d][t] ----------
__global__ __launch_bounds__(256) void tr_v(const float* __restrict__ vp,
                                            short* __restrict__ vt) {
  __shared__ float tile[64][65];
  const int bh = blockIdx.x >> 5;          // 0..15
  const int t0 = (blockIdx.x & 31) << 6;   // 0..2047 step 64
  const float* src = vp + ((size_t)bh * Sdim + t0) * Ddim;
  {
    const int tl = threadIdx.x >> 2;       // 0..63
    const int dg = threadIdx.x & 3;        // 0..3
#pragma unroll
    for (int q = 0; q < 4; ++q) {
      float4 x = *(const float4*)(src + tl * Ddim + dg * 16 + q * 4);
      tile[tl][dg * 16 + q * 4 + 0] = x.x;
      tile[tl][dg * 16 + q * 4 + 1] = x.y;
      tile[tl][dg * 16 + q * 4 + 2] = x.z;
      tile[tl][dg * 16 + q * 4 + 3] = x.w;
    }
  }
  __syncthreads();
  {
    const int d  = threadIdx.x >> 2;       // 0..63
    const int tg = threadIdx.x & 3;        // 16-t chunk
    short* dst = vt + ((size_t)bh * Ddim + d) * Sdim + t0 + tg * 16;
    bf16x8 o0, o1;
#pragma unroll
    for (int j = 0; j < 8; ++j) o0[j] = f2bf(tile[tg * 16 + j][d]);
#pragma unroll
    for (int j = 0; j < 8; ++j) o1[j] = f2bf(tile[tg * 16 + 8 + j][d]);
    *(bf16x8*)(dst) = o0;
    *(bf16x8*)(dst + 8) = o1;
  }
}

// ---------- main kernel ----------
// Per 32-col body: K 4x16B + cov 8 + mask 8 loads prefetched ONE body ahead
// (named scalars -> no scratch); V 4x16B issued at body top BEFORE next
// prefetch so PV's vmcnt wait leaves the prefetch in flight (FIFO).
#define DECLS(S)                                                               \
  bf16x8 kb0a##S, kb0b##S, kb1a##S, kb1b##S;                                   \
  float cv0##S, cv1##S, cv2##S, cv3##S, cv4##S, cv5##S, cv6##S, cv7##S;        \
  int mk0##S, mk1##S, mk2##S, mk3##S, mk4##S, mk5##S, mk6##S, mk7##S;

#define LOADS_KCM(S, T0) {                                                     \
    const int _t = (T0);                                                       \
    kb0a##S = *(const bf16x8*)(kbh + (((size_t)(_t + l15)) << 6) + (quad << 3));        \
    kb0b##S = *(const bf16x8*)(kbh + (((size_t)(_t + l15)) << 6) + (quad << 3) + 32);   \
    kb1a##S = *(const bf16x8*)(kbh + (((size_t)(_t + 16 + l15)) << 6) + (quad << 3));      \
    kb1b##S = *(const bf16x8*)(kbh + (((size_t)(_t + 16 + l15)) << 6) + (quad << 3) + 32); \
    const float* _c = covb + (quad * 4) * Sdim + _t + l15;                     \
    const int*   _m = mb   + (quad * 4) * Sdim + _t + l15;                     \
    cv0##S = _c[0];             mk0##S = _m[0];                                \
    cv1##S = _c[16];            mk1##S = _m[16];                               \
    cv2##S = _c[Sdim];          mk2##S = _m[Sdim];                             \
    cv3##S = _c[Sdim + 16];     mk3##S = _m[Sdim + 16];                        \
    cv4##S = _c[2 * Sdim];      mk4##S = _m[2 * Sdim];                         \
    cv5##S = _c[2 * Sdim + 16]; mk5##S = _m[2 * Sdim + 16];                    \
    cv6##S = _c[3 * Sdim];      mk6##S = _m[3 * Sdim];                         \
    cv7##S = _c[3 * Sdim + 16]; mk7##S = _m[3 * Sdim + 16];                    \
  }

#define LOADS_VB(T0) {                                                         \
    const int _t = (T0);                                                       \
    vb0 = *(const bf16x8*)(vtb + (((size_t)(l15))      << 11) + _t + (quad << 3)); \
    vb1 = *(const bf16x8*)(vtb + (((size_t)(16 + l15)) << 11) + _t + (quad << 3)); \
    vb2 = *(const bf16x8*)(vtb + (((size_t)(32 + l15)) << 11) + _t + (quad << 3)); \
    vb3 = *(const bf16x8*)(vtb + (((size_t)(48 + l15)) << 11) + _t + (quad << 3)); \
  }

#define COMPUTE(S, T0) {                                                       \
    f32x4 a0 = {0.f, 0.f, 0.f, 0.f}, a1 = {0.f, 0.f, 0.f, 0.f};               \
    a0 = __builtin_amdgcn_mfma_f32_16x16x32_bf16(aq0, kb0a##S, a0, 0, 0, 0);   \
    a0 = __builtin_amdgcn_mfma_f32_16x16x32_bf16(aq1, kb0b##S, a0, 0, 0, 0);   \
    a1 = __builtin_amdgcn_mfma_f32_16x16x32_bf16(aq0, kb1a##S, a1, 0, 0, 0);   \
    a1 = __builtin_amdgcn_mfma_f32_16x16x32_bf16(aq1, kb1b##S, a1, 0, 0, 0);   \
    const int col0 = (T0) + l15;                                               \
    const int row0 = quad * 4;                                                 \
    float p;                                                                   \
    p = mk0##S ? __expf(a0[0] + w_cov * cv0##S) : 0.f; lsum[0] += p; Pl[row0 + 0][col0]      = f2bf(p); \
    p = mk1##S ? __expf(a1[0] + w_cov * cv1##S) : 0.f; lsum[0] += p; Pl[row0 + 0][col0 + 16] = f2bf(p); \
    p = mk2##S ? __expf(a0[1] + w_cov * cv2##S) : 0.f; lsum[1] += p; Pl[row0 + 1][col0]      = f2bf(p); \
    p = mk3##S ? __expf(a1[1] + w_cov * cv3##S) : 0.f; lsum[1] += p; Pl[row0 + 1][col0 + 16] = f2bf(p); \
    p = mk4##S ? __expf(a0[2] + w_cov * cv4##S) : 0.f; lsum[2] += p; Pl[row0 + 2][col0]      = f2bf(p); \
    p = mk5##S ? __expf(a1[2] + w_cov * cv5##S) : 0.f; lsum[2] += p; Pl[row0 + 2][col0 + 16] = f2bf(p); \
    p = mk6##S ? __expf(a0[3] + w_cov * cv6##S) : 0.f; lsum[3] += p; Pl[row0 + 3][col0]      = f2bf(p); \
    p = mk7##S ? __expf(a1[3] + w_cov * cv7##S) : 0.f; lsum[3] += p; Pl[row0 + 3][col0 + 16] = f2bf(p); \
    bf16x8 pa = *(const bf16x8*)&Pl[l15][(T0) + quad * 8];                     \
    oacc0 = __builtin_amdgcn_mfma_f32_16x16x32_bf16(pa, vb0, oacc0, 0, 0, 0);  \
    oacc1 = __builtin_amdgcn_mfma_f32_16x16x32_bf16(pa, vb1, oacc1, 0, 0, 0);  \
    oacc2 = __builtin_amdgcn_mfma_f32_16x16x32_bf16(pa, vb2, oacc2, 0, 0, 0);  \
    oacc3 = __builtin_amdgcn_mfma_f32_16x16x32_bf16(pa, vb3, oacc3, 0, 0, 0);  \
  }

__global__ __launch_bounds__(512, 4) void fused_attn(
    const float* __restrict__ qp, const short* __restrict__ kbp,
    const short* __restrict__ vtp, const float* __restrict__ covp,
    const float* __restrict__ lamp, const int* __restrict__ maskp,
    float* __restrict__ outO, float* __restrict__ outA)
{
  __shared__ __align__(16) short Pl[16][PSTR];  // 65792 B -> 2 blocks/CU
  __shared__ float Ls[NW][16];
  __shared__ float Lrow[16];

  const int tid  = threadIdx.x;
  const int wv   = tid >> 6;
  const int lane = tid & 63;
  const int quad = lane >> 4;
  const int l15  = lane & 15;

  // h in low bits (round-2 mapping, empirically best): head h pins to XCD h,
  // K/V working set per XCD ~1 MB -> L2-resident across its 128 q-tiles.
  const int bid = blockIdx.x;
  const int h  = bid & 7;
  const int qt = (bid >> 3) & 127;
  const int b  = bid >> 10;

  const float lam   = lamp[h];
  const float w_qk  = 1.0f / (lam + 1.0f);
  const float w_cov = lam / (lam + 1.0f);
  const float qscale = w_qk * 0.125f;   // fold 1/TEMPERATURE and w_qk into Q

  const int q0 = qt * 16;
  const int bh = b * Hdim + h;

  const float* qbase = qp + ((size_t)bh * Sdim + q0) * Ddim;
  const short* kbh   = kbp + (size_t)bh * Sdim * Ddim;
  const short* vtb   = vtp + (size_t)bh * Ddim * Sdim;
  const float* covb  = covp + ((size_t)b * Sdim + q0) * Sdim;
  const int*   mb    = maskp + ((size_t)b * Sdim + q0) * Sdim;
  float* oA = outA + ((size_t)bh * Sdim + q0) * (size_t)Sdim;
  float* oO = outO + ((size_t)bh * Sdim + q0) * Ddim;

  // Q A-frag (16 rows x 64 k), pre-scaled: A[m=l15][k=quad*8+j]
  bf16x8 aq0, aq1;
  {
    const float* qr = qbase + l15 * Ddim + quad * 8;
    float4 x0 = *(const float4*)(qr);
    float4 x1 = *(const float4*)(qr + 4);
    aq0 = pack8(x0, x1, qscale);
    float4 y0 = *(const float4*)(qr + 32);
    float4 y1 = *(const float4*)(qr + 36);
    aq1 = pack8(y0, y1, qscale);
  }

  const int tbeg = wv * (Sdim / NW);
  const int tend = tbeg + (Sdim / NW);

  float lsum[4] = {0.f, 0.f, 0.f, 0.f};
  f32x4 oacc0 = {0.f, 0.f, 0.f, 0.f}, oacc1 = {0.f, 0.f, 0.f, 0.f};
  f32x4 oacc2 = {0.f, 0.f, 0.f, 0.f}, oacc3 = {0.f, 0.f, 0.f, 0.f};
  bf16x8 vb0, vb1, vb2, vb3;

  DECLS(E)
  DECLS(O)
  LOADS_KCM(E, tbeg)
#pragma unroll 1
  for (int t0 = tbeg; t0 < tend; t0 += 64) {
    LOADS_VB(t0)
    LOADS_KCM(O, t0 + 32)
    COMPUTE(E, t0)
    const int tnx = (t0 + 64 < tend) ? (t0 + 64) : tbeg;  // last prefetch: dummy
    LOADS_VB(t0 + 32)
    LOADS_KCM(E, tnx)
    COMPUTE(O, t0 + 32)
  }

  // ---- cross-wave row-sum reduction ----
#pragma unroll
  for (int r = 0; r < 4; ++r) {
    float s = lsum[r];
    s += __shfl_xor(s, 1, 16);
    s += __shfl_xor(s, 2, 16);
    s += __shfl_xor(s, 4, 16);
    s += __shfl_xor(s, 8, 16);
    if (l15 == 0) Ls[wv][quad * 4 + r] = s;
  }
  __syncthreads();
  if (tid < 16) {
    float s = 0.f;
#pragma unroll
    for (int w2 = 0; w2 < NW; ++w2) s += Ls[w2][tid];
    Lrow[tid] = 1.0f / s;
  }
  __syncthreads();

  // ---- normalize + write attn (each wave: its own 256-col slice, all 16 rows) ----
#pragma unroll 1
  for (int row = 0; row < 16; ++row) {
    const float rinv = Lrow[row];
    float* orow = oA + (size_t)row * Sdim;
    const int c0 = tbeg + lane * 4;
    bf16x4 pv = *(const bf16x4*)&Pl[row][c0];
    f32x4 o;
    o[0] = bf2f(pv[0]) * rinv;
    o[1] = bf2f(pv[1]) * rinv;
    o[2] = bf2f(pv[2]) * rinv;
    o[3] = bf2f(pv[3]) * rinv;
    __builtin_nontemporal_store(o, (f32x4*)&orow[c0]);
  }
  __syncthreads();   // all P reads done; safe to alias

  // ---- O reduction across waves (alias P region), scale by 1/l, store ----
  float* Ored = (float*)&Pl[0][0];   // [NW][64][16] f32 = 32 KB, fits in P alias
#pragma unroll
  for (int r = 0; r < 4; ++r) {
    Ored[((wv * 64 + lane) * 16) + 0  + r] = oacc0[r];
    Ored[((wv * 64 + lane) * 16) + 4  + r] = oacc1[r];
    Ored[((wv * 64 + lane) * 16) + 8  + r] = oacc2[r];
    Ored[((wv * 64 + lane) * 16) + 12 + r] = oacc3[r];
  }
  __syncthreads();
  if (wv < 4) {
#pragma unroll
    for (int r = 0; r < 4; ++r) {
      float s = 0.f;
#pragma unroll
      for (int w2 = 0; w2 < NW; ++w2)
        s += Ored[((w2 * 64 + lane) * 16) + wv * 4 + r];
      const int row = quad * 4 + r;
      __builtin_nontemporal_store(s * Lrow[row], &oO[row * Ddim + wv * 16 + l15]);
    }
  }
}

extern "C" void kernel_launch(void* const* d_in, const int* in_sizes, int n_in,
                              void* d_out, int out_size, void* d_ws, size_t ws_size,
                              hipStream_t stream) {
  const float* q    = (const float*)d_in[0];
  const float* k    = (const float*)d_in[1];
  const float* v    = (const float*)d_in[2];
  const float* cov  = (const float*)d_in[3];
  const float* lam  = (const float*)d_in[4];
  const int*   mask = (const int*)d_in[5];
  float* outO = (float*)d_out;
  float* outA = outO + (size_t)Bdim * Hdim * Sdim * Ddim;

  short* kb = (short*)d_ws;                                  // 4 MB bf16 K
  short* vt = kb + (size_t)Bdim * Hdim * Sdim * Ddim;        // 4 MB bf16 V^T
  (void)ws_size;

  cvt_k<<<dim3((Bdim * Hdim * Sdim * Ddim) / (256 * 8)), 256, 0, stream>>>(k, kb);
  tr_v<<<dim3(Bdim * Hdim * (Sdim / 64)), 256, 0, stream>>>(v, vt);

  dim3 grid(Bdim * Hdim * (Sdim / 16));   // 2048 blocks x 512 threads
  fused_attn<<<grid, 512, 0, stream>>>(q, kb, vt, cov, lam, mask, outO, outA);
}

// Round 5
// 468.452 us; speedup vs baseline: 1.4229x; 1.0733x over previous
//
#include <hip/hip_runtime.h>

#define Bdim 2
#define Hdim 8
#define Sdim 2048
#define Ddim 64
#define PSTR 2056   // P row stride in shorts: +8 pad breaks 16-way bank aliasing
#define NW 8        // waves per block (512 threads)

typedef short bf16x8 __attribute__((ext_vector_type(8)));
typedef short bf16x4 __attribute__((ext_vector_type(4)));
typedef float f32x4 __attribute__((ext_vector_type(4)));

// float -> bf16 bits via hardware cvt (RNE; v_cvt_pk_bf16_f32)
static __device__ __forceinline__ short f2bf(float x) {
  return __builtin_bit_cast(short, (__bf16)x);
}
static __device__ __forceinline__ float bf2f(short x) {
  unsigned u = ((unsigned)(unsigned short)x) << 16;
  return __builtin_bit_cast(float, u);
}
static __device__ __forceinline__ bf16x8 pack8(float4 a, float4 b, float s) {
  bf16x8 r;
  r[0] = f2bf(a.x * s); r[1] = f2bf(a.y * s);
  r[2] = f2bf(a.z * s); r[3] = f2bf(a.w * s);
  r[4] = f2bf(b.x * s); r[5] = f2bf(b.y * s);
  r[6] = f2bf(b.z * s); r[7] = f2bf(b.w * s);
  return r;
}

// ---------- pre-pass 1: K f32 -> bf16, same [b][h][t][d] layout ----------
__global__ __launch_bounds__(256) void cvt_k(const float* __restrict__ kp,
                                             short* __restrict__ kb) {
  size_t i = ((size_t)blockIdx.x * 256 + threadIdx.x) * 8;
  float4 x0 = *(const float4*)(kp + i);
  float4 x1 = *(const float4*)(kp + i + 4);
  bf16x8 r = pack8(x0, x1, 1.0f);
  *(bf16x8*)(kb + i) = r;
}

// ---------- pre-pass 2: V f32 [bh][t][d] -> bf16 [bh][d][t] ----------
__global__ __launch_bounds__(256) void tr_v(const float* __restrict__ vp,
                                            short* __restrict__ vt) {
  __shared__ float tile[64][65];
  const int bh = blockIdx.x >> 5;          // 0..15
  const int t0 = (blockIdx.x & 31) << 6;   // 0..2047 step 64
  const float* src = vp + ((size_t)bh * Sdim + t0) * Ddim;
  {
    const int tl = threadIdx.x >> 2;       // 0..63
    const int dg = threadIdx.x & 3;        // 0..3
#pragma unroll
    for (int q = 0; q < 4; ++q) {
      float4 x = *(const float4*)(src + tl * Ddim + dg * 16 + q * 4);
      tile[tl][dg * 16 + q * 4 + 0] = x.x;
      tile[tl][dg * 16 + q * 4 + 1] = x.y;
      tile[tl][dg * 16 + q * 4 + 2] = x.z;
      tile[tl][dg * 16 + q * 4 + 3] = x.w;
    }
  }
  __syncthreads();
  {
    const int d  = threadIdx.x >> 2;       // 0..63
    const int tg = threadIdx.x & 3;        // 16-t chunk
    short* dst = vt + ((size_t)bh * Ddim + d) * Sdim + t0 + tg * 16;
    bf16x8 o0, o1;
#pragma unroll
    for (int j = 0; j < 8; ++j) o0[j] = f2bf(tile[tg * 16 + j][d]);
#pragma unroll
    for (int j = 0; j < 8; ++j) o1[j] = f2bf(tile[tg * 16 + 8 + j][d]);
    *(bf16x8*)(dst) = o0;
    *(bf16x8*)(dst + 8) = o1;
  }
}

// ---------- pre-pass 3: cov+mask -> covm[(b*128+qt)][col][16 rows] ----------
// covm = mask ? cov : -1e9  (masked logit = acc + w_cov*(-1e9) -> expf -> 0.0f,
// identical to the explicit select for any w_cov >~ 1e-7; lambda=10 here).
// Fragment-order layout: one 64B line holds all 16 rows of a col -> the main
// kernel reads cov as TWO dwordx4 loads per 32-col body instead of 16 dwords.
__global__ __launch_bounds__(256) void cvt_cov(const float* __restrict__ covp,
                                               const int* __restrict__ maskp,
                                               float* __restrict__ cm) {
  const int pair  = blockIdx.x >> 3;            // 0..255 = b*128+qt
  const int chunk = blockIdx.x & 7;
  const int col   = chunk * 256 + threadIdx.x;
  const size_t rowbase = (size_t)pair * 16;     // == (b*Sdim + qt*16)
  float tmp[16];
#pragma unroll
  for (int r = 0; r < 16; ++r) {
    float c = covp[(rowbase + r) * Sdim + col];
    int   m = maskp[(rowbase + r) * Sdim + col];
    tmp[r] = m ? c : -1e9f;
  }
  float* dst = cm + ((size_t)pair * Sdim + col) * 16;
#pragma unroll
  for (int r = 0; r < 16; ++r) dst[r] = tmp[r];
}

// ---------- main kernel ----------
// Per 32-col body: K 4x16B + cov 2x16B prefetched ONE body ahead (named
// scalars -> no scratch); V 4x16B issued at body top BEFORE next prefetch so
// PV's vmcnt wait leaves the prefetch in flight (FIFO).
#define DECLS(S)                                                               \
  bf16x8 kb0a##S, kb0b##S, kb1a##S, kb1b##S;                                   \
  f32x4 cva##S, cvb##S;

#define LOADS_KCM(S, T0) {                                                     \
    const int _t = (T0);                                                       \
    kb0a##S = *(const bf16x8*)(kbh + (((size_t)(_t + l15)) << 6) + (quad << 3));        \
    kb0b##S = *(const bf16x8*)(kbh + (((size_t)(_t + l15)) << 6) + (quad << 3) + 32);   \
    kb1a##S = *(const bf16x8*)(kbh + (((size_t)(_t + 16 + l15)) << 6) + (quad << 3));      \
    kb1b##S = *(const bf16x8*)(kbh + (((size_t)(_t + 16 + l15)) << 6) + (quad << 3) + 32); \
    cva##S = *(const f32x4*)(cmb + (((size_t)(_t + l15)) << 4) + (quad << 2));        \
    cvb##S = *(const f32x4*)(cmb + (((size_t)(_t + 16 + l15)) << 4) + (quad << 2));   \
  }

#define LOADS_VB(T0) {                                                         \
    const int _t = (T0);                                                       \
    vb0 = *(const bf16x8*)(vtb + (((size_t)(l15))      << 11) + _t + (quad << 3)); \
    vb1 = *(const bf16x8*)(vtb + (((size_t)(16 + l15)) << 11) + _t + (quad << 3)); \
    vb2 = *(const bf16x8*)(vtb + (((size_t)(32 + l15)) << 11) + _t + (quad << 3)); \
    vb3 = *(const bf16x8*)(vtb + (((size_t)(48 + l15)) << 11) + _t + (quad << 3)); \
  }

#define COMPUTE(S, T0) {                                                       \
    f32x4 a0 = {0.f, 0.f, 0.f, 0.f}, a1 = {0.f, 0.f, 0.f, 0.f};               \
    a0 = __builtin_amdgcn_mfma_f32_16x16x32_bf16(aq0, kb0a##S, a0, 0, 0, 0);   \
    a0 = __builtin_amdgcn_mfma_f32_16x16x32_bf16(aq1, kb0b##S, a0, 0, 0, 0);   \
    a1 = __builtin_amdgcn_mfma_f32_16x16x32_bf16(aq0, kb1a##S, a1, 0, 0, 0);   \
    a1 = __builtin_amdgcn_mfma_f32_16x16x32_bf16(aq1, kb1b##S, a1, 0, 0, 0);   \
    const int col0 = (T0) + l15;                                               \
    const int row0 = quad * 4;                                                 \
    _Pragma("unroll") for (int r = 0; r < 4; ++r) {                            \
      float p0 = __expf(a0[r] + w_cov * cva##S[r]);                            \
      float p1 = __expf(a1[r] + w_cov * cvb##S[r]);                            \
      lsum[r] += p0 + p1;                                                      \
      Pl[row0 + r][col0]      = f2bf(p0);                                      \
      Pl[row0 + r][col0 + 16] = f2bf(p1);                                      \
    }                                                                          \
    bf16x8 pa = *(const bf16x8*)&Pl[l15][(T0) + quad * 8];                     \
    oacc0 = __builtin_amdgcn_mfma_f32_16x16x32_bf16(pa, vb0, oacc0, 0, 0, 0);  \
    oacc1 = __builtin_amdgcn_mfma_f32_16x16x32_bf16(pa, vb1, oacc1, 0, 0, 0);  \
    oacc2 = __builtin_amdgcn_mfma_f32_16x16x32_bf16(pa, vb2, oacc2, 0, 0, 0);  \
    oacc3 = __builtin_amdgcn_mfma_f32_16x16x32_bf16(pa, vb3, oacc3, 0, 0, 0);  \
  }

__global__ __launch_bounds__(512, 4) void fused_attn(
    const float* __restrict__ qp, const short* __restrict__ kbp,
    const short* __restrict__ vtp, const float* __restrict__ cmp,
    const float* __restrict__ lamp,
    float* __restrict__ outO, float* __restrict__ outA)
{
  __shared__ __align__(16) short Pl[16][PSTR];  // 65792 B -> 2 blocks/CU
  __shared__ float Ls[NW][16];
  __shared__ float Lrow[16];

  const int tid  = threadIdx.x;
  const int wv   = tid >> 6;
  const int lane = tid & 63;
  const int quad = lane >> 4;
  const int l15  = lane & 15;

  // h in low bits (round-2 mapping, empirically best): head h pins to XCD h,
  // K/V working set per XCD ~1 MB -> L2-resident across its 128 q-tiles.
  const int bid = blockIdx.x;
  const int h  = bid & 7;
  const int qt = (bid >> 3) & 127;
  const int b  = bid >> 10;

  const float lam   = lamp[h];
  const float w_qk  = 1.0f / (lam + 1.0f);
  const float w_cov = lam / (lam + 1.0f);
  const float qscale = w_qk * 0.125f;   // fold 1/TEMPERATURE and w_qk into Q

  const int q0 = qt * 16;
  const int bh = b * Hdim + h;

  const float* qbase = qp + ((size_t)bh * Sdim + q0) * Ddim;
  const short* kbh   = kbp + (size_t)bh * Sdim * Ddim;
  const short* vtb   = vtp + (size_t)bh * Ddim * Sdim;
  const float* cmb   = cmp + ((size_t)(b * 128 + qt)) * Sdim * 16;
  float* oA = outA + ((size_t)bh * Sdim + q0) * (size_t)Sdim;
  float* oO = outO + ((size_t)bh * Sdim + q0) * Ddim;

  // Q A-frag (16 rows x 64 k), pre-scaled: A[m=l15][k=quad*8+j]
  bf16x8 aq0, aq1;
  {
    const float* qr = qbase + l15 * Ddim + quad * 8;
    float4 x0 = *(const float4*)(qr);
    float4 x1 = *(const float4*)(qr + 4);
    aq0 = pack8(x0, x1, qscale);
    float4 y0 = *(const float4*)(qr + 32);
    float4 y1 = *(const float4*)(qr + 36);
    aq1 = pack8(y0, y1, qscale);
  }

  const int tbeg = wv * (Sdim / NW);
  const int tend = tbeg + (Sdim / NW);

  float lsum[4] = {0.f, 0.f, 0.f, 0.f};
  f32x4 oacc0 = {0.f, 0.f, 0.f, 0.f}, oacc1 = {0.f, 0.f, 0.f, 0.f};
  f32x4 oacc2 = {0.f, 0.f, 0.f, 0.f}, oacc3 = {0.f, 0.f, 0.f, 0.f};
  bf16x8 vb0, vb1, vb2, vb3;

  DECLS(E)
  DECLS(O)
  LOADS_KCM(E, tbeg)
#pragma unroll 1
  for (int t0 = tbeg; t0 < tend; t0 += 64) {
    LOADS_VB(t0)
    LOADS_KCM(O, t0 + 32)
    COMPUTE(E, t0)
    const int tnx = (t0 + 64 < tend) ? (t0 + 64) : tbeg;  // last prefetch: dummy
    LOADS_VB(t0 + 32)
    LOADS_KCM(E, tnx)
    COMPUTE(O, t0 + 32)
  }

  // ---- cross-wave row-sum reduction ----
#pragma unroll
  for (int r = 0; r < 4; ++r) {
    float s = lsum[r];
    s += __shfl_xor(s, 1, 16);
    s += __shfl_xor(s, 2, 16);
    s += __shfl_xor(s, 4, 16);
    s += __shfl_xor(s, 8, 16);
    if (l15 == 0) Ls[wv][quad * 4 + r] = s;
  }
  __syncthreads();
  if (tid < 16) {
    float s = 0.f;
#pragma unroll
    for (int w2 = 0; w2 < NW; ++w2) s += Ls[w2][tid];
    Lrow[tid] = 1.0f / s;
  }
  __syncthreads();

  // ---- normalize + write attn (each wave: its own 256-col slice, all 16 rows) ----
#pragma unroll 1
  for (int row = 0; row < 16; ++row) {
    const float rinv = Lrow[row];
    float* orow = oA + (size_t)row * Sdim;
    const int c0 = tbeg + lane * 4;
    bf16x4 pv = *(const bf16x4*)&Pl[row][c0];
    f32x4 o;
    o[0] = bf2f(pv[0]) * rinv;
    o[1] = bf2f(pv[1]) * rinv;
    o[2] = bf2f(pv[2]) * rinv;
    o[3] = bf2f(pv[3]) * rinv;
    __builtin_nontemporal_store(o, (f32x4*)&orow[c0]);
  }
  __syncthreads();   // all P reads done; safe to alias

  // ---- O reduction across waves (alias P region), scale by 1/l, store ----
  float* Ored = (float*)&Pl[0][0];   // [NW][64][16] f32 = 32 KB, fits in P alias
#pragma unroll
  for (int r = 0; r < 4; ++r) {
    Ored[((wv * 64 + lane) * 16) + 0  + r] = oacc0[r];
    Ored[((wv * 64 + lane) * 16) + 4  + r] = oacc1[r];
    Ored[((wv * 64 + lane) * 16) + 8  + r] = oacc2[r];
    Ored[((wv * 64 + lane) * 16) + 12 + r] = oacc3[r];
  }
  __syncthreads();
  if (wv < 4) {
#pragma unroll
    for (int r = 0; r < 4; ++r) {
      float s = 0.f;
#pragma unroll
      for (int w2 = 0; w2 < NW; ++w2)
        s += Ored[((w2 * 64 + lane) * 16) + wv * 4 + r];
      const int row = quad * 4 + r;
      __builtin_nontemporal_store(s * Lrow[row], &oO[row * Ddim + wv * 16 + l15]);
    }
  }
}

extern "C" void kernel_launch(void* const* d_in, const int* in_sizes, int n_in,
                              void* d_out, int out_size, void* d_ws, size_t ws_size,
                              hipStream_t stream) {
  const float* q    = (const float*)d_in[0];
  const float* k    = (const float*)d_in[1];
  const float* v    = (const float*)d_in[2];
  const float* cov  = (const float*)d_in[3];
  const float* lam  = (const float*)d_in[4];
  const int*   mask = (const int*)d_in[5];
  float* outO = (float*)d_out;
  float* outA = outO + (size_t)Bdim * Hdim * Sdim * Ddim;

  short* kb = (short*)d_ws;                                  // 4 MB bf16 K
  short* vt = kb + (size_t)Bdim * Hdim * Sdim * Ddim;        // 4 MB bf16 V^T
  float* cm = (float*)(vt + (size_t)Bdim * Hdim * Sdim * Ddim); // 33.5 MB covm
  (void)ws_size;

  cvt_k<<<dim3((Bdim * Hdim * Sdim * Ddim) / (256 * 8)), 256, 0, stream>>>(k, kb);
  tr_v<<<dim3(Bdim * Hdim * (Sdim / 64)), 256, 0, stream>>>(v, vt);
  cvt_cov<<<dim3(Bdim * (Sdim / 16) * 8), 256, 0, stream>>>(cov, mask, cm);

  dim3 grid(Bdim * Hdim * (Sdim / 16));   // 2048 blocks x 512 threads
  fused_attn<<<grid, 512, 0, stream>>>(q, kb, vt, cm, lam, outO, outA);
}

// Round 6
// 458.157 us; speedup vs baseline: 1.4549x; 1.0225x over previous
//
#include <hip/hip_runtime.h>

#define Bdim 2
#define Hdim 8
#define Sdim 2048
#define Ddim 64
#define PSTR 2056   // P row stride in shorts: +8 pad breaks 16-way bank aliasing
#define NW 8        // waves per block (512 threads)

typedef short bf16x8 __attribute__((ext_vector_type(8)));
typedef short bf16x4 __attribute__((ext_vector_type(4)));
typedef float f32x4 __attribute__((ext_vector_type(4)));

// float -> bf16 bits via hardware cvt (RNE; v_cvt_pk_bf16_f32)
static __device__ __forceinline__ short f2bf(float x) {
  return __builtin_bit_cast(short, (__bf16)x);
}
static __device__ __forceinline__ float bf2f(short x) {
  unsigned u = ((unsigned)(unsigned short)x) << 16;
  return __builtin_bit_cast(float, u);
}
static __device__ __forceinline__ bf16x8 pack8(float4 a, float4 b, float s) {
  bf16x8 r;
  r[0] = f2bf(a.x * s); r[1] = f2bf(a.y * s);
  r[2] = f2bf(a.z * s); r[3] = f2bf(a.w * s);
  r[4] = f2bf(b.x * s); r[5] = f2bf(b.y * s);
  r[6] = f2bf(b.z * s); r[7] = f2bf(b.w * s);
  return r;
}

// ---------- pre-pass 1: K f32 -> bf16, same [b][h][t][d] layout ----------
__global__ __launch_bounds__(256) void cvt_k(const float* __restrict__ kp,
                                             short* __restrict__ kb) {
  size_t i = ((size_t)blockIdx.x * 256 + threadIdx.x) * 8;
  float4 x0 = *(const float4*)(kp + i);
  float4 x1 = *(const float4*)(kp + i + 4);
  bf16x8 r = pack8(x0, x1, 1.0f);
  *(bf16x8*)(kb + i) = r;
}

// ---------- pre-pass 2: V f32 [bh][t][d] -> bf16 [bh][d][t] ----------
__global__ __launch_bounds__(256) void tr_v(const float* __restrict__ vp,
                                            short* __restrict__ vt) {
  __shared__ float tile[64][65];
  const int bh = blockIdx.x >> 5;          // 0..15
  const int t0 = (blockIdx.x & 31) << 6;   // 0..2047 step 64
  const float* src = vp + ((size_t)bh * Sdim + t0) * Ddim;
  {
    const int tl = threadIdx.x >> 2;       // 0..63
    const int dg = threadIdx.x & 3;        // 0..3
#pragma unroll
    for (int q = 0; q < 4; ++q) {
      float4 x = *(const float4*)(src + tl * Ddim + dg * 16 + q * 4);
      tile[tl][dg * 16 + q * 4 + 0] = x.x;
      tile[tl][dg * 16 + q * 4 + 1] = x.y;
      tile[tl][dg * 16 + q * 4 + 2] = x.z;
      tile[tl][dg * 16 + q * 4 + 3] = x.w;
    }
  }
  __syncthreads();
  {
    const int d  = threadIdx.x >> 2;       // 0..63
    const int tg = threadIdx.x & 3;        // 16-t chunk
    short* dst = vt + ((size_t)bh * Ddim + d) * Sdim + t0 + tg * 16;
    bf16x8 o0, o1;
#pragma unroll
    for (int j = 0; j < 8; ++j) o0[j] = f2bf(tile[tg * 16 + j][d]);
#pragma unroll
    for (int j = 0; j < 8; ++j) o1[j] = f2bf(tile[tg * 16 + 8 + j][d]);
    *(bf16x8*)(dst) = o0;
    *(bf16x8*)(dst + 8) = o1;
  }
}

// ---------- pre-pass 3: cov+mask -> bf16 covm[(b*128+qt)][col][16 rows] ----------
// covm = bf16(mask ? cov : -1e9). Masked: w_cov*(-1e9-ish) -> expf -> 0.0f.
// bf16 halves cov traffic (33.5->16.7 MB unique; the x8 cross-XCD reads halve too).
__global__ __launch_bounds__(256) void cvt_cov(const float* __restrict__ covp,
                                               const int* __restrict__ maskp,
                                               short* __restrict__ cm) {
  const int pair  = blockIdx.x >> 3;            // 0..255 = b*128+qt
  const int chunk = blockIdx.x & 7;
  const int col   = chunk * 256 + threadIdx.x;
  const size_t rowbase = (size_t)pair * 16;     // == (b*Sdim + qt*16)
  bf16x8 o0, o1;
#pragma unroll
  for (int r = 0; r < 8; ++r) {
    float c = covp[(rowbase + r) * Sdim + col];
    int   m = maskp[(rowbase + r) * Sdim + col];
    o0[r] = f2bf(m ? c : -1e9f);
  }
#pragma unroll
  for (int r = 0; r < 8; ++r) {
    float c = covp[(rowbase + 8 + r) * Sdim + col];
    int   m = maskp[(rowbase + 8 + r) * Sdim + col];
    o1[r] = f2bf(m ? c : -1e9f);
  }
  short* dst = cm + ((size_t)pair * Sdim + col) * 16;
  *(bf16x8*)(dst) = o0;
  *(bf16x8*)(dst + 8) = o1;
}

// ---------- main kernel ----------
// Fully-unrolled 8-body pipeline per wave. Per body i the issue order is
// [K(i+1), V(i+1), C(i+2)] then COMPUTE(i). FIFO vmcnt: QK's wait on K(i)
// drains only C(i) (needed immediately) + K(i); PV's wait on V(i) leaves
// C(i+1),K(i+1),V(i+1),C(i+2) in flight. cov (the only HBM-latency stream)
// gets ~2 bodies of cover; K/V are L2-resident and fine at 1 body.
#define DECL_K(S) bf16x8 k0a##S, k0b##S, k1a##S, k1b##S;
#define DECL_V(S) bf16x8 v0##S, v1##S, v2##S, v3##S;
#define DECL_C(S) bf16x4 ca##S, cb##S;

#define LK(S, T0) {                                                            \
    const int _t = (T0);                                                       \
    k0a##S = *(const bf16x8*)(kbh + (((size_t)(_t + l15)) << 6) + (quad << 3));        \
    k0b##S = *(const bf16x8*)(kbh + (((size_t)(_t + l15)) << 6) + (quad << 3) + 32);   \
    k1a##S = *(const bf16x8*)(kbh + (((size_t)(_t + 16 + l15)) << 6) + (quad << 3));      \
    k1b##S = *(const bf16x8*)(kbh + (((size_t)(_t + 16 + l15)) << 6) + (quad << 3) + 32); \
  }

#define LV(S, T0) {                                                            \
    const int _t = (T0);                                                       \
    v0##S = *(const bf16x8*)(vtb + (((size_t)(l15))      << 11) + _t + (quad << 3)); \
    v1##S = *(const bf16x8*)(vtb + (((size_t)(16 + l15)) << 11) + _t + (quad << 3)); \
    v2##S = *(const bf16x8*)(vtb + (((size_t)(32 + l15)) << 11) + _t + (quad << 3)); \
    v3##S = *(const bf16x8*)(vtb + (((size_t)(48 + l15)) << 11) + _t + (quad << 3)); \
  }

#define LC(S, T0) {                                                            \
    const int _t = (T0);                                                       \
    ca##S = *(const bf16x4*)(cmb + (((size_t)(_t + l15)) << 4) + (quad << 2));      \
    cb##S = *(const bf16x4*)(cmb + (((size_t)(_t + 16 + l15)) << 4) + (quad << 2)); \
  }

#define BODY(KS, VS, CS, T0) {                                                 \
    f32x4 a0 = {0.f, 0.f, 0.f, 0.f}, a1 = {0.f, 0.f, 0.f, 0.f};               \
    a0 = __builtin_amdgcn_mfma_f32_16x16x32_bf16(aq0, k0a##KS, a0, 0, 0, 0);   \
    a0 = __builtin_amdgcn_mfma_f32_16x16x32_bf16(aq1, k0b##KS, a0, 0, 0, 0);   \
    a1 = __builtin_amdgcn_mfma_f32_16x16x32_bf16(aq0, k1a##KS, a1, 0, 0, 0);   \
    a1 = __builtin_amdgcn_mfma_f32_16x16x32_bf16(aq1, k1b##KS, a1, 0, 0, 0);   \
    const int col0 = (T0) + l15;                                               \
    const int row0 = quad * 4;                                                 \
    _Pragma("unroll") for (int r = 0; r < 4; ++r) {                            \
      float p0 = __expf(a0[r] + w_cov * bf2f(ca##CS[r]));                      \
      float p1 = __expf(a1[r] + w_cov * bf2f(cb##CS[r]));                      \
      lsum[r] += p0 + p1;                                                      \
      Pl[row0 + r][col0]      = f2bf(p0);                                      \
      Pl[row0 + r][col0 + 16] = f2bf(p1);                                      \
    }                                                                          \
    bf16x8 pa = *(const bf16x8*)&Pl[l15][(T0) + quad * 8];                     \
    oacc0 = __builtin_amdgcn_mfma_f32_16x16x32_bf16(pa, v0##VS, oacc0, 0, 0, 0); \
    oacc1 = __builtin_amdgcn_mfma_f32_16x16x32_bf16(pa, v1##VS, oacc1, 0, 0, 0); \
    oacc2 = __builtin_amdgcn_mfma_f32_16x16x32_bf16(pa, v2##VS, oacc2, 0, 0, 0); \
    oacc3 = __builtin_amdgcn_mfma_f32_16x16x32_bf16(pa, v3##VS, oacc3, 0, 0, 0); \
  }

__global__ __launch_bounds__(512, 4) void fused_attn(
    const float* __restrict__ qp, const short* __restrict__ kbp,
    const short* __restrict__ vtp, const short* __restrict__ cmp,
    const float* __restrict__ lamp,
    float* __restrict__ outO, float* __restrict__ outA)
{
  __shared__ __align__(16) short Pl[16][PSTR];  // 65792 B -> 2 blocks/CU
  __shared__ float Ls[NW][16];
  __shared__ float Lrow[16];

  const int tid  = threadIdx.x;
  const int wv   = tid >> 6;
  const int lane = tid & 63;
  const int quad = lane >> 4;
  const int l15  = lane & 15;

  // h in low bits: head h pins to XCD h; K/V per XCD ~1 MB -> L2-resident.
  const int bid = blockIdx.x;
  const int h  = bid & 7;
  const int qt = (bid >> 3) & 127;
  const int b  = bid >> 10;

  const float lam   = lamp[h];
  const float w_qk  = 1.0f / (lam + 1.0f);
  const float w_cov = lam / (lam + 1.0f);
  const float qscale = w_qk * 0.125f;   // fold 1/TEMPERATURE and w_qk into Q

  const int q0 = qt * 16;
  const int bh = b * Hdim + h;

  const float* qbase = qp + ((size_t)bh * Sdim + q0) * Ddim;
  const short* kbh   = kbp + (size_t)bh * Sdim * Ddim;
  const short* vtb   = vtp + (size_t)bh * Ddim * Sdim;
  const short* cmb   = cmp + ((size_t)(b * 128 + qt)) * Sdim * 16;
  float* oA = outA + ((size_t)bh * Sdim + q0) * (size_t)Sdim;
  float* oO = outO + ((size_t)bh * Sdim + q0) * Ddim;

  // Q A-frag (16 rows x 64 k), pre-scaled: A[m=l15][k=quad*8+j]
  bf16x8 aq0, aq1;
  {
    const float* qr = qbase + l15 * Ddim + quad * 8;
    float4 x0 = *(const float4*)(qr);
    float4 x1 = *(const float4*)(qr + 4);
    aq0 = pack8(x0, x1, qscale);
    float4 y0 = *(const float4*)(qr + 32);
    float4 y1 = *(const float4*)(qr + 36);
    aq1 = pack8(y0, y1, qscale);
  }

  const int t = wv * (Sdim / NW);   // this wave's 256-col slice

  float lsum[4] = {0.f, 0.f, 0.f, 0.f};
  f32x4 oacc0 = {0.f, 0.f, 0.f, 0.f}, oacc1 = {0.f, 0.f, 0.f, 0.f};
  f32x4 oacc2 = {0.f, 0.f, 0.f, 0.f}, oacc3 = {0.f, 0.f, 0.f, 0.f};

  DECL_K(A) DECL_K(B)
  DECL_V(X) DECL_V(Y)
  DECL_C(c0) DECL_C(c1) DECL_C(c2)

  // prologue
  LK(A, t)         LV(X, t)         LC(c0, t)        LC(c1, t + 32)
  // 8-body pipeline
  LK(B, t + 32)    LV(Y, t + 32)    LC(c2, t + 64)   BODY(A, X, c0, t)
  LK(A, t + 64)    LV(X, t + 64)    LC(c0, t + 96)   BODY(B, Y, c1, t + 32)
  LK(B, t + 96)    LV(Y, t + 96)    LC(c1, t + 128)  BODY(A, X, c2, t + 64)
  LK(A, t + 128)   LV(X, t + 128)   LC(c2, t + 160)  BODY(B, Y, c0, t + 96)
  LK(B, t + 160)   LV(Y, t + 160)   LC(c0, t + 192)  BODY(A, X, c1, t + 128)
  LK(A, t + 192)   LV(X, t + 192)   LC(c1, t + 224)  BODY(B, Y, c2, t + 160)
  LK(B, t + 224)   LV(Y, t + 224)                    BODY(A, X, c0, t + 192)
                                                     BODY(B, Y, c1, t + 224)

  // ---- cross-wave row-sum reduction ----
#pragma unroll
  for (int r = 0; r < 4; ++r) {
    float s = lsum[r];
    s += __shfl_xor(s, 1, 16);
    s += __shfl_xor(s, 2, 16);
    s += __shfl_xor(s, 4, 16);
    s += __shfl_xor(s, 8, 16);
    if (l15 == 0) Ls[wv][quad * 4 + r] = s;
  }
  __syncthreads();
  if (tid < 16) {
    float s = 0.f;
#pragma unroll
    for (int w2 = 0; w2 < NW; ++w2) s += Ls[w2][tid];
    Lrow[tid] = 1.0f / s;
  }
  __syncthreads();

  // ---- normalize + write attn (each wave: its own 256-col slice, all 16 rows) ----
#pragma unroll 1
  for (int row = 0; row < 16; ++row) {
    const float rinv = Lrow[row];
    float* orow = oA + (size_t)row * Sdim;
    const int c0 = t + lane * 4;
    bf16x4 pv = *(const bf16x4*)&Pl[row][c0];
    f32x4 o;
    o[0] = bf2f(pv[0]) * rinv;
    o[1] = bf2f(pv[1]) * rinv;
    o[2] = bf2f(pv[2]) * rinv;
    o[3] = bf2f(pv[3]) * rinv;
    __builtin_nontemporal_store(o, (f32x4*)&orow[c0]);
  }
  __syncthreads();   // all P reads done; safe to alias

  // ---- O reduction across waves (alias P region), scale by 1/l, store ----
  float* Ored = (float*)&Pl[0][0];   // [NW][64][16] f32 = 32 KB, fits in P alias
#pragma unroll
  for (int r = 0; r < 4; ++r) {
    Ored[((wv * 64 + lane) * 16) + 0  + r] = oacc0[r];
    Ored[((wv * 64 + lane) * 16) + 4  + r] = oacc1[r];
    Ored[((wv * 64 + lane) * 16) + 8  + r] = oacc2[r];
    Ored[((wv * 64 + lane) * 16) + 12 + r] = oacc3[r];
  }
  __syncthreads();
  if (wv < 4) {
#pragma unroll
    for (int r = 0; r < 4; ++r) {
      float s = 0.f;
#pragma unroll
      for (int w2 = 0; w2 < NW; ++w2)
        s += Ored[((w2 * 64 + lane) * 16) + wv * 4 + r];
      const int row = quad * 4 + r;
      __builtin_nontemporal_store(s * Lrow[row], &oO[row * Ddim + wv * 16 + l15]);
    }
  }
}

extern "C" void kernel_launch(void* const* d_in, const int* in_sizes, int n_in,
                              void* d_out, int out_size, void* d_ws, size_t ws_size,
                              hipStream_t stream) {
  const float* q    = (const float*)d_in[0];
  const float* k    = (const float*)d_in[1];
  const float* v    = (const float*)d_in[2];
  const float* cov  = (const float*)d_in[3];
  const float* lam  = (const float*)d_in[4];
  const int*   mask = (const int*)d_in[5];
  float* outO = (float*)d_out;
  float* outA = outO + (size_t)Bdim * Hdim * Sdim * Ddim;

  short* kb = (short*)d_ws;                                  // 4 MB bf16 K
  short* vt = kb + (size_t)Bdim * Hdim * Sdim * Ddim;        // 4 MB bf16 V^T
  short* cm = vt + (size_t)Bdim * Hdim * Sdim * Ddim;        // 16.7 MB bf16 covm
  (void)ws_size;

  cvt_k<<<dim3((Bdim * Hdim * Sdim * Ddim) / (256 * 8)), 256, 0, stream>>>(k, kb);
  tr_v<<<dim3(Bdim * Hdim * (Sdim / 64)), 256, 0, stream>>>(v, vt);
  cvt_cov<<<dim3(Bdim * (Sdim / 16) * 8), 256, 0, stream>>>(cov, mask, cm);

  dim3 grid(Bdim * Hdim * (Sdim / 16));   // 2048 blocks x 512 threads
  fused_attn<<<grid, 512, 0, stream>>>(q, kb, vt, cm, lam, outO, outA);
}